// Round 2
// baseline (58775.641 us; speedup 1.0000x reference)
//
#include <hip/hip_runtime.h>

// MI-LSTM, B=32, T=512, H=1024, L=2.  Persistent-kernel, split-bf16 precision:
//  - 256 blocks x 256 threads, 1 block/CU (forced by ~149 KB LDS) -> all co-resident.
//  - Each block owns 16 gate-columns; W0/U0/W1/U1 *hi* slices live in LDS as bf16 (128 KB).
//    *lo* slices (bf16 residual) stream from a 32 MB ws buffer (L3-resident).
//  - GEMMs use 2-way split-bf16, 3 MFMAs per tile: ah*bh + al*bh + ah*bl  (~2^-16 exact).
//    h is carried fp32 (LDS) and published as hi/lo bf16 planes; x split in-register.
//  - Tick loop (513): phase A = gates for layer0@t and layer1@t-1; phase B = LN/pointwise
//    (blocks 0..31: layer0 rows, 32..63: layer1 rows). Hierarchical device barrier with
//    explicit __threadfence release/acquire (cross-XCD L2 safety).

#define TSTEPS 512
#define BATCH  32
#define HDIM   1024
#define GDIM   4096
#define NBLK   256
#define NTHR   256
#define CPB    16
#define KPAD   1032

typedef __attribute__((ext_vector_type(8))) short short8;
typedef __attribute__((ext_vector_type(4))) float f32x4;

// ---- ws layout (bytes) ----
#define WLO_OFF   0u            // 4 mats * 4096 * 1024 * 2 B = 33,554,432
#define H0HI_OFF  33554432u     // 32*1024*2 = 65536 each
#define H0LO_OFF  33619968u
#define H1HI_OFF  33685504u
#define H1LO_OFF  33751040u
#define G0_OFF    33816576u     // 32*4096*4 = 524288
#define G1_OFF    34340864u
#define SYNC_OFF  34865152u     // cnts (9 x 128 B) + gen
#define SMEM_BYTES 152608

__device__ __forceinline__ unsigned f2bf(float f) {
  unsigned u = __float_as_uint(f);
  return (u + 0x7FFFu + ((u >> 16) & 1u)) >> 16;   // RNE fp32 -> bf16 bits
}
__device__ __forceinline__ float sigm(float x) { return 1.f / (1.f + __expf(-x)); }
__device__ __forceinline__ float tanh_(float x) { return 1.f - 2.f / (__expf(2.f * x) + 1.f); }

__device__ __forceinline__ void split8(float4 a, float4 b, short8& hi, short8& lo) {
  float f[8] = {a.x, a.y, a.z, a.w, b.x, b.y, b.z, b.w};
  #pragma unroll
  for (int i = 0; i < 8; ++i) {
    unsigned h = f2bf(f[i]);
    hi[i] = (short)h;
    lo[i] = (short)f2bf(f[i] - __uint_as_float(h << 16));
  }
}

// Hierarchical device barrier: 8 groups of 32 -> root. Explicit fences for
// cross-XCD visibility (release: wbl2 before arrive; acquire: inv after pass).
__device__ __forceinline__ void dev_barrier(unsigned* cnts, unsigned* gen) {
  __syncthreads();                 // all block stores drained to L2 (vmcnt(0))
  if (threadIdx.x == 0) {
    __threadfence();               // agent-scope release: L2 -> L3 writeback
    unsigned g = __hip_atomic_load(gen, __ATOMIC_RELAXED, __HIP_MEMORY_SCOPE_AGENT);
    int grp = blockIdx.x >> 5;     // 8 groups of 32 blocks
    unsigned a = __hip_atomic_fetch_add(&cnts[grp * 32], 1u, __ATOMIC_ACQ_REL,
                                        __HIP_MEMORY_SCOPE_AGENT);
    if (a == 31u) {
      __hip_atomic_store(&cnts[grp * 32], 0u, __ATOMIC_RELAXED, __HIP_MEMORY_SCOPE_AGENT);
      unsigned r = __hip_atomic_fetch_add(&cnts[8 * 32], 1u, __ATOMIC_ACQ_REL,
                                          __HIP_MEMORY_SCOPE_AGENT);
      if (r == 7u) {
        __hip_atomic_store(&cnts[8 * 32], 0u, __ATOMIC_RELAXED, __HIP_MEMORY_SCOPE_AGENT);
        __hip_atomic_store(gen, g + 1u, __ATOMIC_RELEASE, __HIP_MEMORY_SCOPE_AGENT);
      }
    }
    while (__hip_atomic_load(gen, __ATOMIC_ACQUIRE, __HIP_MEMORY_SCOPE_AGENT) == g)
      __builtin_amdgcn_s_sleep(2);
    __threadfence();               // agent-scope acquire: invalidate L1/L2
  }
  __syncthreads();
}

__device__ __forceinline__ void bred(float& s, float& q, volatile float* red, int tid) {
  #pragma unroll
  for (int o = 32; o > 0; o >>= 1) {
    s += __shfl_xor(s, o, 64);
    q += __shfl_xor(q, o, 64);
  }
  __syncthreads();
  if ((tid & 63) == 0) { int w = tid >> 6; red[w] = s; red[w + 4] = q; }
  __syncthreads();
  s = red[0] + red[1] + red[2] + red[3];
  q = red[4] + red[5] + red[6] + red[7];
}

__device__ __forceinline__ void pointwise(
    int l, int r, int t, const float* __restrict__ gates,
    const float* __restrict__ lngw, const float* __restrict__ lngb,
    const float* __restrict__ lncw, const float* __restrict__ lncb,
    unsigned short* __restrict__ hhi, unsigned short* __restrict__ hlo,
    float* __restrict__ y,
    float* lnbuf, float* clds, volatile float* red, int tid)
{
  const float* grow = gates + (size_t)r * GDIM;
  float vals[16];
  float s = 0.f, qq = 0.f;
  #pragma unroll
  for (int i = 0; i < 16; ++i) {
    float v = grow[tid + i * NTHR];
    vals[i] = v; s += v; qq += v * v;
  }
  bred(s, qq, red, tid);
  float m1  = s * (1.f / (float)GDIM);
  float var = qq * (1.f / (float)GDIM) - m1 * m1;
  float inv = rsqrtf(var + 1e-5f);
  #pragma unroll
  for (int i = 0; i < 16; ++i) {
    int j = tid + i * NTHR;
    lnbuf[j] = (vals[i] - m1) * inv * lngw[l * GDIM + j] + lngb[l * GDIM + j];
  }
  __syncthreads();
  float cv[4];
  float s2 = 0.f, q2 = 0.f;
  #pragma unroll
  for (int i = 0; i < 4; ++i) {
    int j = tid + i * NTHR;
    float gi = sigm(lnbuf[j]);            // i gate
    float gf = sigm(lnbuf[j + 1024]);     // f gate
    float gg = tanh_(lnbuf[j + 2048]);    // g gate
    float c  = gf * clds[j] + gi * gg;
    cv[i] = c; s2 += c; q2 += c * c;
  }
  bred(s2, q2, red, tid);
  float m2   = s2 * (1.f / (float)HDIM);
  float v2   = q2 * (1.f / (float)HDIM) - m2 * m2;
  float inv2 = rsqrtf(v2 + 1e-5f);
  #pragma unroll
  for (int i = 0; i < 4; ++i) {
    int j = tid + i * NTHR;
    float cn = (cv[i] - m2) * inv2 * lncw[l * HDIM + j] + lncb[l * HDIM + j];
    clds[j] = cn;                                   // carried state (post-LN, as in ref)
    float h = sigm(lnbuf[j + 3072]) * tanh_(cn);    // o gate
    unsigned hh = f2bf(h);
    hhi[r * HDIM + j] = (unsigned short)hh;
    hlo[r * HDIM + j] = (unsigned short)f2bf(h - __uint_as_float(hh << 16));
    if (y) y[((size_t)r * TSTEPS + t) * HDIM + j] = h;
  }
}

extern "C" __global__ void __launch_bounds__(NTHR)
milstm_main(const float* __restrict__ x,
            const float* __restrict__ Wm, const float* __restrict__ bv,
            const float* __restrict__ Um,
            const float* __restrict__ lngw, const float* __restrict__ lngb,
            const float* __restrict__ lncw, const float* __restrict__ lncb,
            const unsigned short* __restrict__ wlo,
            unsigned short* __restrict__ h0hi, unsigned short* __restrict__ h0lo,
            unsigned short* __restrict__ h1hi, unsigned short* __restrict__ h1lo,
            float* __restrict__ gates0, float* __restrict__ gates1,
            unsigned* cnts, unsigned* gen, float* __restrict__ y)
{
  extern __shared__ unsigned char smem[];
  unsigned short* wlds = (unsigned short*)smem;            // 4*16*1032*2 = 132096 B
  float* lnbuf = (float*)(smem + 132096);                  // 16384 B
  float* clds  = (float*)(smem + 148480);                  // 4096 B
  float* red   = (float*)(smem + 152576);                  // 32 B

  const int tid = threadIdx.x;
  const int bk  = blockIdx.x;
  const int c0  = bk * CPB;

  // ---- preload hi-part weight slices into LDS ----
  // mat: 0=W0 1=U0 2=W1 3=U1 ; layout [mat][col][k+pad]
  #pragma unroll 4
  for (int it = 0; it < 64; ++it) {
    int idx = it * NTHR + tid;
    int mat = idx >> 12;
    int rem = idx & 4095;
    int row = rem >> 8;
    int k4  = rem & 255;
    int l   = mat >> 1;
    const float* src = ((mat & 1) ? Um : Wm) + (size_t)(l * GDIM + c0 + row) * HDIM + k4 * 4;
    float4 f = *(const float4*)src;
    uint2 u;
    u.x = f2bf(f.x) | (f2bf(f.y) << 16);
    u.y = f2bf(f.z) | (f2bf(f.w) << 16);
    *(uint2*)(wlds + (size_t)(mat * CPB + row) * KPAD + k4 * 4) = u;
  }
  for (int i = tid; i < HDIM; i += NTHR) clds[i] = 0.f;    // c-state = 0
  __syncthreads();

  const int lane = tid & 63;
  const int wv   = tid >> 6;
  const int L    = wv >> 1;       // layer for this wave in phase A
  const int mt   = wv & 1;        // M-tile (batch rows 0..15 / 16..31)
  const int q    = lane >> 4;
  const int r16  = lane & 15;
  const int arow = mt * 16 + r16;

  const unsigned short* bxh = wlds + (size_t)((L * 2 + 0) * CPB + r16) * KPAD + q * 8;
  const unsigned short* buh = wlds + (size_t)((L * 2 + 1) * CPB + r16) * KPAD + q * 8;
  const unsigned short* bxl = wlo + ((size_t)((L * 2 + 0) * GDIM) + c0 + r16) * HDIM + q * 8;
  const unsigned short* bul = wlo + ((size_t)((L * 2 + 1) * GDIM) + c0 + r16) * HDIM + q * 8;
  const float bias_v = bv[L * GDIM + c0 + r16];

  for (int tk = 0; tk <= TSTEPS; ++tk) {
    // -------- phase A: split-bf16 gates GEMMs (layer0@tk, layer1@tk-1) --------
    const bool act = (L == 0) ? (tk < TSTEPS) : (tk >= 1);
    if (act) {
      f32x4 accx = {0.f, 0.f, 0.f, 0.f};
      f32x4 acch = {0.f, 0.f, 0.f, 0.f};
      if (L == 0) {
        const float* xp = x + ((size_t)arow * TSTEPS + tk) * HDIM + q * 8;
        const unsigned short* hh = h0hi + arow * HDIM + q * 8;
        const unsigned short* hl = h0lo + arow * HDIM + q * 8;
        #pragma unroll 4
        for (int ch = 0; ch < 32; ++ch) {
          float4 fa = *(const float4*)(xp + ch * 32);
          float4 fb = *(const float4*)(xp + ch * 32 + 4);
          short8 axh, axl; split8(fa, fb, axh, axl);
          short8 ahh = *(const short8*)(hh + ch * 32);
          short8 ahl = *(const short8*)(hl + ch * 32);
          short8 wh = *(const short8*)(bxh + ch * 32);
          short8 wl = *(const short8*)(bxl + ch * 32);
          short8 uh = *(const short8*)(buh + ch * 32);
          short8 ul = *(const short8*)(bul + ch * 32);
          accx = __builtin_amdgcn_mfma_f32_16x16x32_bf16(axh, wh, accx, 0, 0, 0);
          accx = __builtin_amdgcn_mfma_f32_16x16x32_bf16(axl, wh, accx, 0, 0, 0);
          accx = __builtin_amdgcn_mfma_f32_16x16x32_bf16(axh, wl, accx, 0, 0, 0);
          acch = __builtin_amdgcn_mfma_f32_16x16x32_bf16(ahh, uh, acch, 0, 0, 0);
          acch = __builtin_amdgcn_mfma_f32_16x16x32_bf16(ahl, uh, acch, 0, 0, 0);
          acch = __builtin_amdgcn_mfma_f32_16x16x32_bf16(ahh, ul, acch, 0, 0, 0);
        }
      } else {
        const unsigned short* gh_ = h0hi + arow * HDIM + q * 8;
        const unsigned short* gl_ = h0lo + arow * HDIM + q * 8;
        const unsigned short* hh  = h1hi + arow * HDIM + q * 8;
        const unsigned short* hl  = h1lo + arow * HDIM + q * 8;
        #pragma unroll 4
        for (int ch = 0; ch < 32; ++ch) {
          short8 axh = *(const short8*)(gh_ + ch * 32);
          short8 axl = *(const short8*)(gl_ + ch * 32);
          short8 ahh = *(const short8*)(hh + ch * 32);
          short8 ahl = *(const short8*)(hl + ch * 32);
          short8 wh = *(const short8*)(bxh + ch * 32);
          short8 wl = *(const short8*)(bxl + ch * 32);
          short8 uh = *(const short8*)(buh + ch * 32);
          short8 ul = *(const short8*)(bul + ch * 32);
          accx = __builtin_amdgcn_mfma_f32_16x16x32_bf16(axh, wh, accx, 0, 0, 0);
          accx = __builtin_amdgcn_mfma_f32_16x16x32_bf16(axl, wh, accx, 0, 0, 0);
          accx = __builtin_amdgcn_mfma_f32_16x16x32_bf16(axh, wl, accx, 0, 0, 0);
          acch = __builtin_amdgcn_mfma_f32_16x16x32_bf16(ahh, uh, acch, 0, 0, 0);
          acch = __builtin_amdgcn_mfma_f32_16x16x32_bf16(ahl, uh, acch, 0, 0, 0);
          acch = __builtin_amdgcn_mfma_f32_16x16x32_bf16(ahh, ul, acch, 0, 0, 0);
        }
      }
      float* gbuf = (L == 0) ? gates0 : gates1;
      #pragma unroll
      for (int rg = 0; rg < 4; ++rg) {
        float gx = accx[rg] + bias_v;     // gx = x@W.T + b
        float gh = acch[rg];
        int row = mt * 16 + q * 4 + rg;   // C/D: col=lane&15, row=quad*4+reg
        gbuf[row * GDIM + c0 + r16] = gx + gh + gx * gh;   // multiplicative integration
      }
    }
    dev_barrier(cnts, gen);

    // -------- phase B: pointwise/LN --------
    if (bk < BATCH) {
      if (tk < TSTEPS)
        pointwise(0, bk, tk, gates0, lngw, lngb, lncw, lncb, h0hi, h0lo, (float*)0,
                  lnbuf, clds, red, tid);
    } else if (bk < 2 * BATCH) {
      if (tk >= 1)
        pointwise(1, bk - BATCH, tk - 1, gates1, lngw, lngb, lncw, lncb, h1hi, h1lo, y,
                  lnbuf, clds, red, tid);
    }
    dev_barrier(cnts, gen);
  }
}

// residual (lo) part of all four weight matrices -> bf16, layout [mat][col][k]
extern "C" __global__ void __launch_bounds__(256)
milstm_prep_wlo(const float* __restrict__ Wm, const float* __restrict__ Um,
                unsigned short* __restrict__ wlo)
{
  int v = blockIdx.x * 256 + threadIdx.x;    // 0 .. 4*4096*256-1, one float4 each
  int mat = v >> 20;
  int rem = v & 1048575;
  int col = rem >> 8;
  int k4  = rem & 255;
  const float* src = ((mat & 1) ? Um : Wm) + (size_t)((mat >> 1) * GDIM + col) * HDIM + k4 * 4;
  float4 f = *(const float4*)src;
  float fv[4] = {f.x, f.y, f.z, f.w};
  unsigned lo[4];
  #pragma unroll
  for (int i = 0; i < 4; ++i) {
    unsigned h = f2bf(fv[i]);
    lo[i] = f2bf(fv[i] - __uint_as_float(h << 16));
  }
  uint2 u;
  u.x = lo[0] | (lo[1] << 16);
  u.y = lo[2] | (lo[3] << 16);
  *(uint2*)(wlo + ((size_t)mat * GDIM + col) * HDIM + k4 * 4) = u;
}

extern "C" __global__ void __launch_bounds__(256)
milstm_prep_init(unsigned* __restrict__ hz, unsigned* __restrict__ sync)
{
  int v = blockIdx.x * 256 + threadIdx.x;
  if (v < 65536) hz[v] = 0u;                     // h0/h1 hi+lo planes (262144 B)
  else if (v < 66560) sync[v - 65536] = 0u;      // barrier state (4096 B)
}

extern "C" void kernel_launch(void* const* d_in, const int* in_sizes, int n_in,
                              void* d_out, int out_size, void* d_ws, size_t ws_size,
                              hipStream_t stream)
{
  const float* x    = (const float*)d_in[0];
  const float* Wm   = (const float*)d_in[1];
  const float* bv   = (const float*)d_in[2];
  const float* Um   = (const float*)d_in[3];
  const float* lngw = (const float*)d_in[4];
  const float* lngb = (const float*)d_in[5];
  const float* lncw = (const float*)d_in[6];
  const float* lncb = (const float*)d_in[7];
  float* y = (float*)d_out;

  unsigned char* ws = (unsigned char*)d_ws;
  unsigned short* wlo  = (unsigned short*)(ws + WLO_OFF);
  unsigned short* h0hi = (unsigned short*)(ws + H0HI_OFF);
  unsigned short* h0lo = (unsigned short*)(ws + H0LO_OFF);
  unsigned short* h1hi = (unsigned short*)(ws + H1HI_OFF);
  unsigned short* h1lo = (unsigned short*)(ws + H1LO_OFF);
  float* gates0 = (float*)(ws + G0_OFF);
  float* gates1 = (float*)(ws + G1_OFF);
  unsigned* cnts = (unsigned*)(ws + SYNC_OFF);
  unsigned* gen  = (unsigned*)(ws + SYNC_OFF + 2048);

  hipLaunchKernelGGL(milstm_prep_wlo, dim3(16384), dim3(256), 0, stream, Wm, Um, wlo);
  hipLaunchKernelGGL(milstm_prep_init, dim3(260), dim3(256), 0, stream,
                     (unsigned*)h0hi, cnts);
  (void)hipFuncSetAttribute((const void*)milstm_main,
                            hipFuncAttributeMaxDynamicSharedMemorySize, SMEM_BYTES);
  hipLaunchKernelGGL(milstm_main, dim3(NBLK), dim3(NTHR), SMEM_BYTES, stream,
                     x, Wm, bv, Um, lngw, lngb, lncw, lncb, wlo,
                     h0hi, h0lo, h1hi, h1lo, gates0, gates1, cnts, gen, y);
}

// Round 4
// 21553.888 us; speedup vs baseline: 2.7269x; 2.7269x over previous
//
#include <hip/hip_runtime.h>

// MI-LSTM, B=32, T=512, H=1024, L=2.  Persistent kernel, fence-free coherence:
//  - 256 blocks x 256 thr, 1 block/CU (149 KB LDS). Weights hi-bf16 in LDS (128 KB/CU),
//    lo-residual streamed from ws (L2/L3-resident; no L2 invalidates -> stays cached).
//  - Split-bf16 GEMM (3 MFMA: ah*bh + al*bh + ah*bl) => fp32-grade gates.
//  - gates: cross-XCD via RELAXED AGENT atomics (scope bits bypass local L2 -> MALL).
//  - phase B (LN+pointwise) replicated per XCD (slot = HW_REG_XCC_ID, rank via census):
//    h hi/lo planes are per-XCD copies, same-L2 coherent, PLAIN stores/loads.
//    Parity double-buffer on gates and h planes; buffer_inv sc0 (L1-only) per barrier.
//  - Barriers: relaxed monotonic counters, per-slot tree -> root, epoch = tick+1.

#define TSTEPS 512
#define BATCH  32
#define HDIM   1024
#define GDIM   4096
#define NBLK   256
#define NTHR   256
#define CPB    16
#define KPAD   1032   // elements; row stride 2064 B (16B aligned)

typedef __attribute__((ext_vector_type(8))) short short8;
typedef __attribute__((ext_vector_type(4))) float f32x4;

// ---- ws layout (bytes) ----
#define WLO_OFF   0u           // 32 MB: lo-residual of W0,U0,W1,U1  [mat][col][k] bf16
#define HPL_OFF   33554432u    // 4 MB: h planes [slot(8)][parity(2)][plane(4)] 64 KB each
#define G_OFF     37748736u    // 2 MB: gates [layer(2)][parity(2)] 512 KB each
#define SYNC_OFF  39845888u    // 4 KB sync words
#define SMEM_BYTES 152640

// sync word indices (4B units, 64B-spaced lines)
#define SW_CENSUS(s)  ((s) * 16)
#define SW_FCNT       128
#define SW_SCNT(s)    (144 + (s) * 16)
#define SW_ROOT       272
#define SW_LCNT(s)    (288 + (s) * 16)

#define AT_RLX __ATOMIC_RELAXED
#define SC_AGT __HIP_MEMORY_SCOPE_AGENT

__device__ __forceinline__ unsigned f2bf(float f) {
  unsigned u = __float_as_uint(f);
  return (u + 0x7FFFu + ((u >> 16) & 1u)) >> 16;   // RNE fp32 -> bf16 bits
}
__device__ __forceinline__ float sigm(float x) { return 1.f / (1.f + __expf(-x)); }
__device__ __forceinline__ float tanh_(float x) { return 1.f - 2.f / (__expf(2.f * x) + 1.f); }

__device__ __forceinline__ void split8(float4 a, float4 b, short8& hi, short8& lo) {
  float f[8] = {a.x, a.y, a.z, a.w, b.x, b.y, b.z, b.w};
  #pragma unroll
  for (int i = 0; i < 8; ++i) {
    unsigned h = f2bf(f[i]);
    hi[i] = (short)h;
    lo[i] = (short)f2bf(f[i] - __uint_as_float(h << 16));
  }
}

__device__ __forceinline__ int xcc_id() {
  // s_getreg(HW_REG_XCC_ID=20, offset 0, size 4)
  return (int)(__builtin_amdgcn_s_getreg(20 | (3 << 11)) & 7);
}

__device__ __forceinline__ unsigned short* hplane(unsigned char* hbase, int slot, int par, int pl) {
  return (unsigned short*)(hbase + ((unsigned)((slot * 8 + par * 4 + pl)) << 16));
}
__device__ __forceinline__ float* gbase(unsigned char* gb, int l, int par) {
  return (float*)(gb + ((unsigned)(l * 2 + par) << 19));
}

// global barrier #ep (ep = 1,2,...): per-slot monotonic counter -> root.
__device__ __forceinline__ void gbar(unsigned* sync, int slot, int n, int nslots, unsigned ep) {
  __syncthreads();                       // compiler emits vmcnt(0) drain before s_barrier
  if (threadIdx.x == 0) {
    unsigned a = __hip_atomic_fetch_add(sync + SW_SCNT(slot), 1u, AT_RLX, SC_AGT);
    if (a == (unsigned)n * ep - 1u)      // last arriver of this slot for barrier #ep
      __hip_atomic_fetch_add(sync + SW_ROOT, 1u, AT_RLX, SC_AGT);
    while (__hip_atomic_load(sync + SW_ROOT, AT_RLX, SC_AGT) < (unsigned)nslots * ep)
      __builtin_amdgcn_s_sleep(4);
  }
  __syncthreads();
  asm volatile("buffer_inv sc0" ::: "memory");           // L1-only invalidate
}

// XCD-local barrier: monotonic per-slot counter, target = n * (tick+1)
__device__ __forceinline__ void lbar(unsigned* sync, int slot, unsigned target) {
  __syncthreads();
  if (threadIdx.x == 0) {
    __hip_atomic_fetch_add(sync + SW_LCNT(slot), 1u, AT_RLX, SC_AGT);
    while (__hip_atomic_load(sync + SW_LCNT(slot), AT_RLX, SC_AGT) < target)
      __builtin_amdgcn_s_sleep(2);
  }
  __syncthreads();
  asm volatile("buffer_inv sc0" ::: "memory");           // L1-only invalidate
}

__device__ __forceinline__ void bred(float& s, float& q, volatile float* red, int tid) {
  #pragma unroll
  for (int o = 32; o > 0; o >>= 1) {
    s += __shfl_xor(s, o, 64);
    q += __shfl_xor(q, o, 64);
  }
  __syncthreads();
  if ((tid & 63) == 0) { int w = tid >> 6; red[w] = s; red[w + 4] = q; }
  __syncthreads();
  s = red[0] + red[1] + red[2] + red[3];
  q = red[4] + red[5] + red[6] + red[7];
  __syncthreads();
}

// Register-resident pointwise: thread t owns columns {t+256k}; its 16 gate values are
// exactly i/f/g/o for those 4 columns (i = cols 0..1023, f 1024.., g 2048.., o 3072..).
__device__ __forceinline__ void pointwise2(
    int l, int r, int t, float* __restrict__ gbuf,
    const float* __restrict__ lngw, const float* __restrict__ lngb,
    const float* __restrict__ lncw, const float* __restrict__ lncb,
    unsigned short* __restrict__ hhi, unsigned short* __restrict__ hlo,
    float* __restrict__ y, float* cst, volatile float* red, int tid)
{
  float* grow = gbuf + (size_t)r * GDIM;
  float vals[16];
  float s = 0.f, qq = 0.f;
  #pragma unroll
  for (int i = 0; i < 16; ++i) {
    float v = __hip_atomic_load(grow + tid + i * NTHR, AT_RLX, SC_AGT);  // bypass L2 (MALL)
    vals[i] = v; s += v; qq += v * v;
  }
  bred(s, qq, red, tid);
  float m1  = s * (1.f / (float)GDIM);
  float var = qq * (1.f / (float)GDIM) - m1 * m1;
  float inv = rsqrtf(var + 1e-5f);
  float ln[16];
  #pragma unroll
  for (int i = 0; i < 16; ++i) {
    int col = tid + i * NTHR;
    ln[i] = (vals[i] - m1) * inv * lngw[l * GDIM + col] + lngb[l * GDIM + col];
  }
  float cv[4];
  float s2 = 0.f, q2 = 0.f;
  #pragma unroll
  for (int k = 0; k < 4; ++k) {
    int j = tid + k * NTHR;
    float gi = sigm(ln[k]);          // i gate (cols 0..1023)
    float gf = sigm(ln[4 + k]);      // f gate
    float gg = tanh_(ln[8 + k]);     // g gate
    float c  = gf * cst[j] + gi * gg;
    cv[k] = c; s2 += c; q2 += c * c;
  }
  bred(s2, q2, red, tid);
  float m2   = s2 * (1.f / (float)HDIM);
  float v2   = q2 * (1.f / (float)HDIM) - m2 * m2;
  float inv2 = rsqrtf(v2 + 1e-5f);
  #pragma unroll
  for (int k = 0; k < 4; ++k) {
    int j = tid + k * NTHR;
    float cn = (cv[k] - m2) * inv2 * lncw[l * HDIM + j] + lncb[l * HDIM + j];
    cst[j] = cn;                                   // carried state (post-LN, as in ref)
    float h = sigm(ln[12 + k]) * tanh_(cn);        // o gate
    unsigned hh = f2bf(h);
    // PLAIN stores: same-XCD consumers read through the shared L2 (coherent);
    // consumer L1 staleness handled by buffer_inv sc0 at the barrier.
    hhi[r * HDIM + j] = (unsigned short)hh;
    hlo[r * HDIM + j] = (unsigned short)f2bf(h - __uint_as_float(hh << 16));
    if (y) y[((size_t)r * TSTEPS + t) * HDIM + j] = h;
  }
}

extern "C" __global__ void __launch_bounds__(NTHR)
milstm_main(const float* __restrict__ x,
            const float* __restrict__ Wm, const float* __restrict__ bv,
            const float* __restrict__ Um,
            const float* __restrict__ lngw, const float* __restrict__ lngb,
            const float* __restrict__ lncw, const float* __restrict__ lncb,
            unsigned char* __restrict__ ws, float* __restrict__ y)
{
  extern __shared__ unsigned char smem[];
  unsigned short* wlds = (unsigned short*)smem;            // 132096 B
  float* clds = (float*)(smem + 132096);                   // 5 * 4096 B c-state slots
  volatile float* red = (volatile float*)(smem + 152576);  // 64 B

  const unsigned short* wlo = (const unsigned short*)(ws + WLO_OFF);
  unsigned char* hbase = ws + HPL_OFF;
  unsigned char* gb    = ws + G_OFF;
  unsigned* sync       = (unsigned*)(ws + SYNC_OFF);

  const int tid = threadIdx.x;
  const int bk  = blockIdx.x;
  const int c0  = bk * CPB;

  // ---- preload hi-part weight slices into LDS (mat: 0=W0 1=U0 2=W1 3=U1) ----
  #pragma unroll 4
  for (int it = 0; it < 64; ++it) {
    int idx = it * NTHR + tid;
    int mat = idx >> 12;
    int rem = idx & 4095;
    int row = rem >> 8;
    int k4  = rem & 255;
    int l   = mat >> 1;
    const float* src = ((mat & 1) ? Um : Wm) + (size_t)(l * GDIM + c0 + row) * HDIM + k4 * 4;
    float4 f = *(const float4*)src;
    uint2 u;
    u.x = f2bf(f.x) | (f2bf(f.y) << 16);
    u.y = f2bf(f.z) | (f2bf(f.w) << 16);
    *(uint2*)(wlds + (size_t)(mat * CPB + row) * KPAD + k4 * 4) = u;
  }
  for (int i = tid; i < 5 * HDIM; i += NTHR) clds[i] = 0.f;   // c-state = 0

  // ---- census: slot (XCD) + rank within slot ----
  __shared__ int sh_slot, sh_rank, sh_n, sh_nslots;
  __syncthreads();
  if (tid == 0) {
    int s = xcc_id();
    sh_slot = s;
    sh_rank = (int)__hip_atomic_fetch_add(sync + SW_CENSUS(s), 1u, AT_RLX, SC_AGT);
    __hip_atomic_fetch_add(sync + SW_FCNT, 1u, AT_RLX, SC_AGT);
    while (__hip_atomic_load(sync + SW_FCNT, AT_RLX, SC_AGT) < (unsigned)NBLK)
      __builtin_amdgcn_s_sleep(4);
    asm volatile("" ::: "memory");
    int ns = 0, nn = 0;
    for (int i = 0; i < 8; ++i) {
      int c = (int)__hip_atomic_load(sync + SW_CENSUS(i), AT_RLX, SC_AGT);
      if (c > 0) ns++;
      if (i == s) nn = c;
    }
    sh_n = nn; sh_nslots = ns;
  }
  __syncthreads();
  const int slot = sh_slot, rank = sh_rank, n = sh_n, nslots = sh_nslots;

  const int lane = tid & 63;
  const int wv   = tid >> 6;
  const int Lw   = wv >> 1;       // layer for this wave in phase A
  const int mt   = wv & 1;        // M-tile (batch rows 0..15 / 16..31)
  const int q    = lane >> 4;
  const int r16  = lane & 15;
  const int arow = mt * 16 + r16;

  const unsigned short* bxh = wlds + (size_t)((Lw * 2 + 0) * CPB + r16) * KPAD + q * 8;
  const unsigned short* buh = wlds + (size_t)((Lw * 2 + 1) * CPB + r16) * KPAD + q * 8;
  const unsigned short* bxl = wlo + ((size_t)((Lw * 2 + 0) * GDIM) + c0 + r16) * HDIM + q * 8;
  const unsigned short* bul = wlo + ((size_t)((Lw * 2 + 1) * GDIM) + c0 + r16) * HDIM + q * 8;
  const float bias_v = bv[Lw * GDIM + c0 + r16];

  for (int tk = 0; tk <= TSTEPS; ++tk) {
    // -------- phase A: split-bf16 gates GEMMs (layer0@tk, layer1@tk-1) --------
    const bool act = (Lw == 0) ? (tk < TSTEPS) : (tk >= 1);
    if (act) {
      // h input parities: h0@tk-1 -> (tk+1)&1 ; h1@tk-2 -> tk&1
      const unsigned short* p0hi = hplane(hbase, slot, (tk + 1) & 1, 0);
      const unsigned short* p0lo = hplane(hbase, slot, (tk + 1) & 1, 1);
      f32x4 accx = {0.f, 0.f, 0.f, 0.f};
      f32x4 acch = {0.f, 0.f, 0.f, 0.f};
      if (Lw == 0) {
        const float* xp = x + ((size_t)arow * TSTEPS + tk) * HDIM + q * 8;
        const unsigned short* hh = p0hi + arow * HDIM + q * 8;
        const unsigned short* hl = p0lo + arow * HDIM + q * 8;
        #pragma unroll 4
        for (int ch = 0; ch < 32; ++ch) {
          float4 fa = *(const float4*)(xp + ch * 32);
          float4 fb = *(const float4*)(xp + ch * 32 + 4);
          short8 axh, axl; split8(fa, fb, axh, axl);
          short8 ahh = *(const short8*)(hh + ch * 32);
          short8 ahl = *(const short8*)(hl + ch * 32);
          short8 wh = *(const short8*)(bxh + ch * 32);
          short8 wl = *(const short8*)(bxl + ch * 32);
          short8 uh = *(const short8*)(buh + ch * 32);
          short8 ul = *(const short8*)(bul + ch * 32);
          accx = __builtin_amdgcn_mfma_f32_16x16x32_bf16(axh, wh, accx, 0, 0, 0);
          accx = __builtin_amdgcn_mfma_f32_16x16x32_bf16(axl, wh, accx, 0, 0, 0);
          accx = __builtin_amdgcn_mfma_f32_16x16x32_bf16(axh, wl, accx, 0, 0, 0);
          acch = __builtin_amdgcn_mfma_f32_16x16x32_bf16(ahh, uh, acch, 0, 0, 0);
          acch = __builtin_amdgcn_mfma_f32_16x16x32_bf16(ahl, uh, acch, 0, 0, 0);
          acch = __builtin_amdgcn_mfma_f32_16x16x32_bf16(ahh, ul, acch, 0, 0, 0);
        }
      } else {
        const unsigned short* p1hi = hplane(hbase, slot, tk & 1, 2);
        const unsigned short* p1lo = hplane(hbase, slot, tk & 1, 3);
        const unsigned short* gh_ = p0hi + arow * HDIM + q * 8;
        const unsigned short* gl_ = p0lo + arow * HDIM + q * 8;
        const unsigned short* hh  = p1hi + arow * HDIM + q * 8;
        const unsigned short* hl  = p1lo + arow * HDIM + q * 8;
        #pragma unroll 4
        for (int ch = 0; ch < 32; ++ch) {
          short8 axh = *(const short8*)(gh_ + ch * 32);
          short8 axl = *(const short8*)(gl_ + ch * 32);
          short8 ahh = *(const short8*)(hh + ch * 32);
          short8 ahl = *(const short8*)(hl + ch * 32);
          short8 wh = *(const short8*)(bxh + ch * 32);
          short8 wl = *(const short8*)(bxl + ch * 32);
          short8 uh = *(const short8*)(buh + ch * 32);
          short8 ul = *(const short8*)(bul + ch * 32);
          accx = __builtin_amdgcn_mfma_f32_16x16x32_bf16(axh, wh, accx, 0, 0, 0);
          accx = __builtin_amdgcn_mfma_f32_16x16x32_bf16(axl, wh, accx, 0, 0, 0);
          accx = __builtin_amdgcn_mfma_f32_16x16x32_bf16(axh, wl, accx, 0, 0, 0);
          acch = __builtin_amdgcn_mfma_f32_16x16x32_bf16(ahh, uh, acch, 0, 0, 0);
          acch = __builtin_amdgcn_mfma_f32_16x16x32_bf16(ahl, uh, acch, 0, 0, 0);
          acch = __builtin_amdgcn_mfma_f32_16x16x32_bf16(ahh, ul, acch, 0, 0, 0);
        }
      }
      float* gbuf = (Lw == 0) ? gbase(gb, 0, tk & 1) : gbase(gb, 1, (tk - 1) & 1);
      #pragma unroll
      for (int rg = 0; rg < 4; ++rg) {
        float gx = accx[rg] + bias_v;     // gx = x@W.T + b
        float gh = acch[rg];
        int row = mt * 16 + q * 4 + rg;   // C/D: col=lane&15, row=quad*4+reg
        __hip_atomic_store(&gbuf[row * GDIM + c0 + r16], gx + gh + gx * gh, AT_RLX, SC_AGT);
      }
    }
    gbar(sync, slot, n, nslots, (unsigned)(tk + 1));

    // -------- phase B: replicated per XCD; rank r takes tasks r, r+n, ... of 64 --------
    for (int task = rank; task < 64; task += n) {
      int o = (task - rank) / n;
      if (o >= 5) break;                  // c-state LDS capacity guard
      int l = task >> 5, r = task & 31;
      float* cst = clds + o * HDIM;
      if (l == 0) {
        if (tk < TSTEPS)
          pointwise2(0, r, tk, gbase(gb, 0, tk & 1), lngw, lngb, lncw, lncb,
                     hplane(hbase, slot, tk & 1, 0), hplane(hbase, slot, tk & 1, 1),
                     (float*)0, cst, red, tid);
      } else {
        if (tk >= 1)
          pointwise2(1, r, tk - 1, gbase(gb, 1, (tk - 1) & 1), lngw, lngb, lncw, lncb,
                     hplane(hbase, slot, (tk - 1) & 1, 2), hplane(hbase, slot, (tk - 1) & 1, 3),
                     y, cst, red, tid);
      }
    }
    lbar(sync, slot, (unsigned)n * (unsigned)(tk + 1));
  }
}

// lo-residual of the four weight matrices -> bf16, layout [mat][col][k]
extern "C" __global__ void __launch_bounds__(256)
milstm_prep_wlo(const float* __restrict__ Wm, const float* __restrict__ Um,
                unsigned short* __restrict__ wlo)
{
  int v = blockIdx.x * 256 + threadIdx.x;    // one float4 each
  int mat = v >> 20;
  int rem = v & 1048575;
  int col = rem >> 8;
  int k4  = rem & 255;
  const float* src = ((mat & 1) ? Um : Wm) + (size_t)((mat >> 1) * GDIM + col) * HDIM + k4 * 4;
  float4 f = *(const float4*)src;
  float fv[4] = {f.x, f.y, f.z, f.w};
  unsigned lo[4];
  #pragma unroll
  for (int i = 0; i < 4; ++i) {
    unsigned h = f2bf(fv[i]);
    lo[i] = f2bf(fv[i] - __uint_as_float(h << 16));
  }
  uint2 u;
  u.x = lo[0] | (lo[1] << 16);
  u.y = lo[2] | (lo[3] << 16);
  *(uint2*)(wlo + ((size_t)mat * GDIM + col) * HDIM + k4 * 4) = u;
}

extern "C" __global__ void __launch_bounds__(256)
milstm_prep_init(unsigned* __restrict__ hz, unsigned* __restrict__ sync)
{
  int v = blockIdx.x * 256 + threadIdx.x;
  if (v < 1048576) hz[v] = 0u;                    // h planes region (4 MB)
  else if (v < 1048576 + 1024) sync[v - 1048576] = 0u;   // sync words (4 KB)
}

extern "C" void kernel_launch(void* const* d_in, const int* in_sizes, int n_in,
                              void* d_out, int out_size, void* d_ws, size_t ws_size,
                              hipStream_t stream)
{
  const float* x    = (const float*)d_in[0];
  const float* Wm   = (const float*)d_in[1];
  const float* bv   = (const float*)d_in[2];
  const float* Um   = (const float*)d_in[3];
  const float* lngw = (const float*)d_in[4];
  const float* lngb = (const float*)d_in[5];
  const float* lncw = (const float*)d_in[6];
  const float* lncb = (const float*)d_in[7];
  float* y = (float*)d_out;

  unsigned char* ws = (unsigned char*)d_ws;
  unsigned short* wlo = (unsigned short*)(ws + WLO_OFF);
  unsigned* hz   = (unsigned*)(ws + HPL_OFF);
  unsigned* sync = (unsigned*)(ws + SYNC_OFF);

  hipLaunchKernelGGL(milstm_prep_wlo, dim3(16384), dim3(256), 0, stream, Wm, Um, wlo);
  hipLaunchKernelGGL(milstm_prep_init, dim3(4101), dim3(256), 0, stream, hz, sync);
  (void)hipFuncSetAttribute((const void*)milstm_main,
                            hipFuncAttributeMaxDynamicSharedMemorySize, SMEM_BYTES);
  hipLaunchKernelGGL(milstm_main, dim3(NBLK), dim3(NTHR), SMEM_BYTES, stream,
                     x, Wm, bv, Um, lngw, lngb, lncw, lncb, ws, y);
}